// Round 5
// baseline (5870.885 us; speedup 1.0000x reference)
//
#include <hip/hip_runtime.h>

#define BB 256
#define NN 512
#define DD 128
#define HH 8

static constexpr float NEGC = -1e9f;
static constexpr float INV_SQRT_D = 0.08838834764831845f; // 1/sqrt(128)

__device__ __forceinline__ float dot4(float4 a, float4 b) {
    return a.x * b.x + a.y * b.y + a.z * b.z + a.w * b.w;
}
__device__ __forceinline__ void fma4(float4& a, float p, float4 e) {
    a.x += p * e.x; a.y += p * e.y; a.z += p * e.z; a.w += p * e.w;
}

// ---------------- precompute: fixed_ctx = mean_n(E) @ W_fixed ----------------
__global__ __launch_bounds__(128)
void precompute_fc(const float* __restrict__ E, const float* __restrict__ Wf,
                   float* __restrict__ fc) {
    int b = blockIdx.x, d = threadIdx.x;
    __shared__ float ge[DD];
    const float* Eb = E + (size_t)b * NN * DD;
    float s = 0.f;
    for (int n = 0; n < NN; ++n) s += Eb[n * DD + d];
    ge[d] = s * (1.0f / 512.0f);
    __syncthreads();
    float o = 0.f;
    for (int k = 0; k < DD; ++k) o += ge[k] * Wf[k * DD + d];
    fc[b * DD + d] = o;
}

// ---- precompute: WkT[k][d] = W_node[d][k] (k<128);  W_og = W_out @ Wl^T ----
__global__ __launch_bounds__(128)
void precompute_w(const float* __restrict__ Wn, const float* __restrict__ Wout,
                  float* __restrict__ Wog, float* __restrict__ WkT) {
    int k = blockIdx.x, d = threadIdx.x;
    WkT[k * DD + d] = Wn[d * 384 + k];
    float s = 0.f;
    for (int e = 0; e < DD; ++e) s += Wout[k * DD + e] * Wn[d * 384 + 256 + e];
    Wog[k * DD + d] = s;
}

// ---------------------------- main decoder ----------------------------------
// LDS budget (161,828 B <= 163,840):
//   tl      2*512*32*4 = 131072  (E d-slice tiles; aliased as wpart after accumB)
//   P       8*516*4    =  16512  (pad 516 -> bank (4h+n): conflict-free)
//   qt/eb   2*4096, part/part2 2*2048, qarr/fcs/curE 3*512, lw 256, misc ~280
struct SM {
    float tl[2][NN][32];
    float P[HH][516];
    float qt[HH][DD];
    float eb[HH][DD];
    float part[4][DD];
    float part2[4][DD];
    float qarr[DD];        // q, later reused as g~
    float fcs[DD];
    float curE[DD];
    float lw[8][8];
    float redf[16];
    float redv[8];
    int   redi[8];
    float Mh[HH];
    float stat[2];
    int   cur;
    float rbv;
};

// amdgpu_waves_per_eu(1,2): cap occupancy target at 2 waves/SIMD -> register
// budget 256 VGPR/thread. __launch_bounds__(512,{1,2}) only sets the MIN
// waves/EU (a floor), so the allocator kept the 128-VGPR/4-wave target and
// spilled er[32] to scratch (rounds 3-4: FETCH 5.4 GB, VALUBusy 14.6%).
// Occupancy is LDS-limited to 1 block/CU (162 KB) = 2 waves/SIMD anyway.
__global__ __attribute__((amdgpu_flat_work_group_size(512, 512)))
           __attribute__((amdgpu_waves_per_eu(1, 2)))
void decoder(const float* __restrict__ E, const float* __restrict__ Ws,
             const float* __restrict__ Wn, const float* __restrict__ fc,
             const float* __restrict__ Wog, const float* __restrict__ WkT,
             float* __restrict__ out_logp, float* __restrict__ out_seq, int T) {
    __shared__ SM sm;
    const int b = blockIdx.x, tid = threadIdx.x;
    const int lane = tid & 63, wv = tid >> 6;
    const int g4 = tid >> 7, d128 = tid & 127;
    const float* Eb = E + (size_t)b * NN * DD;

    // ---- init: stage E through LDS (coalesced global, swizzled LDS) into regs ----
    float4 er[32];                       // this thread's E row (row n = tid)
    {
        const float4* Ef4 = (const float4*)Eb;
        float4* tls = (float4*)&sm.tl[0][0][0];
        #pragma unroll
        for (int s = 0; s < 4; ++s) {
            #pragma unroll
            for (int i = 0; i < 8; ++i) {
                int f = i * 512 + tid;
                int n = f >> 3, c = f & 7;
                tls[n * 8 + (c ^ (n & 7))] = Ef4[n * 32 + s * 8 + c];
            }
            __syncthreads();
            #pragma unroll
            for (int c = 0; c < 8; ++c)
                er[s * 8 + c] = tls[tid * 8 + (c ^ (tid & 7))];
            __syncthreads();
        }
    }
    bool vis = false;
    if (tid < DD) sm.fcs[tid] = fc[b * DD + tid];
    // Rb = max_n ||E[n]||  (from registers)
    {
        float s = 0.f;
        #pragma unroll
        for (int j = 0; j < 32; ++j) s += dot4(er[j], er[j]);
        for (int o = 1; o < 64; o <<= 1) s = fmaxf(s, __shfl_xor(s, o));
        if (lane == 0) sm.redf[wv] = s;
    }
    if (tid == 0) {
        sm.cur = 0;
        #pragma unroll
        for (int j = 0; j < 32; ++j) *(float4*)&sm.curE[4 * j] = er[j];
    }
    __syncthreads();
    if (tid == 0) {
        float m = sm.redf[0];
        for (int i = 1; i < 8; ++i) m = fmaxf(m, sm.redf[i]);
        sm.rbv = sqrtf(m);
    }
    __syncthreads();

    for (int t = 0; t < T; ++t) {
        // ---- phase 0: q = fc + E[cur]@Ws + frac*Ws_last ----
        {
            float s = 0.f;
            const float* Wsg = Ws + d128;
            int k0 = g4 * 32;
            #pragma unroll 8
            for (int k = k0; k < k0 + 32; ++k) s += sm.curE[k] * Wsg[k * DD];
            if (g4 == 3) s += ((float)t / (float)T) * Wsg[128 * DD];
            sm.part[g4][d128] = s;
        }
        __syncthreads();
        if (tid < DD)
            sm.qarr[tid] = sm.fcs[tid] + sm.part[0][tid] + sm.part[1][tid]
                         + sm.part[2][tid] + sm.part[3][tid];
        __syncthreads();
        // ---- phase 0b: qt (0.25 folded) + Cauchy-Schwarz safe max ----
        {
            const int hA = g4, hB = g4 + 4;
            const float* WA = WkT + (hA * 16) * DD + d128;
            const float* WB = WkT + (hB * 16) * DD + d128;
            float a = 0.f, c = 0.f;
            #pragma unroll
            for (int j = 0; j < 16; ++j) {
                a += sm.qarr[hA * 16 + j] * WA[j * DD];
                c += sm.qarr[hB * 16 + j] * WB[j * DD];
            }
            a *= 0.25f; c *= 0.25f;
            sm.qt[hA][d128] = a;
            sm.qt[hB][d128] = c;
            float sa = a * a, sc = c * c;
            for (int o = 1; o < 64; o <<= 1) {
                sa += __shfl_xor(sa, o);
                sc += __shfl_xor(sc, o);
            }
            if (lane == 0) { sm.redf[wv] = sa; sm.redf[8 + wv] = sc; }
        }
        __syncthreads();
        if (tid < 8) {
            int h = tid;
            float ss = (h < 4) ? (sm.redf[2 * h] + sm.redf[2 * h + 1])
                               : (sm.redf[8 + 2 * (h - 4)] + sm.redf[8 + 2 * (h - 4) + 1]);
            sm.Mh[h] = sqrtf(ss) * sm.rbv;
        }
        __syncthreads();

        // ---- compat + exp entirely from registers; P[h][n] to LDS ----
        for (int h = 0; h < 8; ++h) {
            const float4* qh = (const float4*)&sm.qt[h][0];
            float s0 = 0.f, s1 = 0.f, s2 = 0.f, s3 = 0.f;
            #pragma unroll
            for (int j = 0; j < 32; j += 4) {
                s0 += dot4(qh[j], er[j]);
                s1 += dot4(qh[j + 1], er[j + 1]);
                s2 += dot4(qh[j + 2], er[j + 2]);
                s3 += dot4(qh[j + 3], er[j + 3]);
            }
            float cs = (s0 + s1) + (s2 + s3);
            float p = vis ? 0.0f : expf(cs - sm.Mh[h]);
            sm.P[h][tid] = p;
        }
        __syncthreads();

        // ---- e-bar: reg->LDS d-slice tiles (XOR-swizzled), n-split over waves ----
        float4 acc[4];
        float lacc = 0.f;
        const int eh = lane >> 3, edq = lane & 7;   // (head, d-quad)
        acc[0] = acc[1] = acc[2] = acc[3] = make_float4(0.f, 0.f, 0.f, 0.f);
        // slices 0,1
        #pragma unroll
        for (int c = 0; c < 8; ++c) {
            *(float4*)&sm.tl[0][tid][(c ^ (tid & 7)) * 4] = er[c];
            *(float4*)&sm.tl[1][tid][(c ^ (tid & 7)) * 4] = er[8 + c];
        }
        __syncthreads();
        {
            int nb = wv * 64;
            #pragma unroll 8
            for (int i = 0; i < 64; ++i) {
                int n = nb + i;
                float pv = sm.P[eh][n];
                float4 e0 = *(const float4*)&sm.tl[0][n][(edq ^ (n & 7)) * 4];
                float4 e1 = *(const float4*)&sm.tl[1][n][(edq ^ (n & 7)) * 4];
                fma4(acc[0], pv, e0);
                fma4(acc[1], pv, e1);
                lacc += pv;
            }
        }
        __syncthreads();
        // slices 2,3
        #pragma unroll
        for (int c = 0; c < 8; ++c) {
            *(float4*)&sm.tl[0][tid][(c ^ (tid & 7)) * 4] = er[16 + c];
            *(float4*)&sm.tl[1][tid][(c ^ (tid & 7)) * 4] = er[24 + c];
        }
        __syncthreads();
        {
            int nb = wv * 64;
            #pragma unroll 8
            for (int i = 0; i < 64; ++i) {
                int n = nb + i;
                float pv = sm.P[eh][n];
                float4 e2 = *(const float4*)&sm.tl[0][n][(edq ^ (n & 7)) * 4];
                float4 e3 = *(const float4*)&sm.tl[1][n][(edq ^ (n & 7)) * 4];
                fma4(acc[2], pv, e2);
                fma4(acc[3], pv, e3);
            }
        }
        __syncthreads();   // tiles dead; tl region becomes wpart
        {
            float* wp = &sm.tl[0][0][0];
            float* wpe = wp + (size_t)(wv * 64 + lane) * 20;   // 20-float stride: 8-quad spread
            #pragma unroll
            for (int s = 0; s < 4; ++s) *(float4*)&wpe[4 * s] = acc[s];
            if (edq == 0) sm.lw[wv][eh] = lacc;
        }
        __syncthreads();
        {   // combine 8 wave-partials -> eb[h][d], normalized by l[h]
            const float* wp = &sm.tl[0][0][0];
            int h = tid >> 6;
            int dbase = (tid & 63) * 2;
            float lsum = 0.f;
            #pragma unroll
            for (int w = 0; w < 8; ++w) lsum += sm.lw[w][h];
            float inv = 1.0f / lsum;
            #pragma unroll
            for (int r = 0; r < 2; ++r) {
                int d = dbase + r;
                int s = d >> 5, dq = (d >> 2) & 7, comp = d & 3;
                float a = 0.f;
                #pragma unroll
                for (int w = 0; w < 8; ++w)
                    a += wp[(size_t)(w * 64 + h * 8 + dq) * 20 + s * 4 + comp];
                sm.eb[h][d] = a * inv;
            }
        }
        __syncthreads();

        // ---- phase 2: heads = eb @ Wv ; g~ = heads @ W_og ----
        {
            float s = 0.f;
            int k0 = g4 * 32;
            const int hh = d128 >> 4;
            const float* Wv = Wn + 128 + d128;
            #pragma unroll 8
            for (int d = k0; d < k0 + 32; ++d) s += sm.eb[hh][d] * Wv[d * 384];
            sm.part[g4][d128] = s;
        }
        __syncthreads();
        {
            float s = 0.f;
            int k0 = g4 * 32;
            #pragma unroll 8
            for (int k = k0; k < k0 + 32; ++k) {
                float hcv = sm.part[0][k] + sm.part[1][k] + sm.part[2][k] + sm.part[3][k];
                s += hcv * Wog[k * DD + d128];
            }
            sm.part2[g4][d128] = s;
        }
        __syncthreads();
        if (tid < DD)
            sm.qarr[tid] = (sm.part2[0][tid] + sm.part2[1][tid] + sm.part2[2][tid]
                          + sm.part2[3][tid]) * INV_SQRT_D;   // qarr reused as g~
        __syncthreads();

        // ---- logits from registers ----
        float logit;
        {
            const float4* gv = (const float4*)&sm.qarr[0];
            float s0 = 0.f, s1 = 0.f, s2 = 0.f, s3 = 0.f;
            #pragma unroll
            for (int j = 0; j < 32; j += 4) {
                s0 += dot4(gv[j], er[j]);
                s1 += dot4(gv[j + 1], er[j + 1]);
                s2 += dot4(gv[j + 2], er[j + 2]);
                s3 += dot4(gv[j + 3], er[j + 3]);
            }
            float s = (s0 + s1) + (s2 + s3);
            logit = vis ? NEGC : 10.0f * tanhf(s);
        }

        // ---- phase 4: log_softmax + write + argmax + update (structure preserved) ----
        {
            float x = logit;
            float m = x;
            for (int o = 1; o < 64; o <<= 1) m = fmaxf(m, __shfl_xor(m, o));
            if (lane == 0) sm.redf[wv] = m;
            __syncthreads();
            if (tid == 0) {
                float mm = sm.redf[0];
                for (int i = 1; i < 8; ++i) mm = fmaxf(mm, sm.redf[i]);
                sm.stat[0] = mm;
            }
            __syncthreads();
            float mm = sm.stat[0];
            float sh = x - mm;                 // masked: -1e9 - mm rounds to -1e9
            float ex = expf(sh);               // masked: exactly 0
            float ssum = ex;
            for (int o = 1; o < 64; o <<= 1) ssum += __shfl_xor(ssum, o);
            if (lane == 0) sm.redf[wv] = ssum;
            __syncthreads();
            if (tid == 0) {
                float s8 = 0.f;
                for (int i = 0; i < 8; ++i) s8 += sm.redf[i];
                sm.stat[1] = logf(s8);
            }
            __syncthreads();
            float lse = sm.stat[1];
            float lp = sh - lse;
            out_logp[((size_t)b * T + t) * NN + tid] = lp;
            float bv = lp; int bi = tid;
            for (int o = 1; o < 64; o <<= 1) {
                float ov = __shfl_xor(bv, o);
                int   oi = __shfl_xor(bi, o);
                if (ov > bv || (ov == bv && oi < bi)) { bv = ov; bi = oi; }
            }
            if (lane == 0) { sm.redv[wv] = bv; sm.redi[wv] = bi; }
            __syncthreads();
            if (tid == 0) {
                float best = sm.redv[0]; int besti = sm.redi[0];
                for (int i = 1; i < 8; ++i) {
                    float ov = sm.redv[i]; int oi = sm.redi[i];
                    if (ov > best || (ov == best && oi < besti)) { best = ov; besti = oi; }
                }
                sm.cur = besti;
                out_seq[(size_t)b * T + t] = (float)besti;
            }
            __syncthreads();
            if (tid == sm.cur) {               // selected thread broadcasts its row
                vis = true;
                #pragma unroll
                for (int j = 0; j < 32; ++j) *(float4*)&sm.curE[4 * j] = er[j];
            }
            __syncthreads();
        }
    }
}

// ------------------------------- launcher -----------------------------------
extern "C" void kernel_launch(void* const* d_in, const int* in_sizes, int n_in,
                              void* d_out, int out_size, void* d_ws, size_t ws_size,
                              hipStream_t stream) {
    const float* E    = (const float*)d_in[0];   // [B,N,D]
    const float* Wn   = (const float*)d_in[1];   // [D,3D]
    const float* Wf   = (const float*)d_in[2];   // [D,D]
    const float* Ws   = (const float*)d_in[3];   // [D+1,D]
    const float* Wout = (const float*)d_in[4];   // [D,D]
    float* out = (float*)d_out;

    const int T = out_size / (BB * (NN + 1));    // = num_steps (64)

    float* fc  = (float*)d_ws;                   // [B,D]
    float* Wog = fc + BB * DD;                   // [128,128]
    float* WkT = Wog + DD * DD;                  // [128,128]

    precompute_fc<<<BB, 128, 0, stream>>>(E, Wf, fc);
    precompute_w<<<DD, 128, 0, stream>>>(Wn, Wout, Wog, WkT);
    decoder<<<BB, 512, 0, stream>>>(E, Ws, Wn, fc, Wog, WkT,
                                    out, out + (size_t)BB * T * NN, T);
}

// Round 6
// 2794.683 us; speedup vs baseline: 2.1007x; 2.1007x over previous
//
#include <hip/hip_runtime.h>

#define BB 256
#define NN 512
#define DD 128
#define HH 8

static constexpr float NEGC = -1e9f;
static constexpr float INV_SQRT_D = 0.08838834764831845f; // 1/sqrt(128)

__device__ __forceinline__ float dot4(float4 a, float4 b) {
    return a.x * b.x + a.y * b.y + a.z * b.z + a.w * b.w;
}

#define FOR16(OP) OP(0) OP(1) OP(2) OP(3) OP(4) OP(5) OP(6) OP(7) \
                  OP(8) OP(9) OP(10) OP(11) OP(12) OP(13) OP(14) OP(15)

// ---------------- precompute: fixed_ctx = mean_n(E) @ W_fixed ----------------
__global__ __launch_bounds__(128)
void precompute_fc(const float* __restrict__ E, const float* __restrict__ Wf,
                   float* __restrict__ fc) {
    int b = blockIdx.x, d = threadIdx.x;
    __shared__ float ge[DD];
    const float* Eb = E + (size_t)b * NN * DD;
    float s = 0.f;
    for (int n = 0; n < NN; ++n) s += Eb[n * DD + d];
    ge[d] = s * (1.0f / 512.0f);
    __syncthreads();
    float o = 0.f;
    for (int k = 0; k < DD; ++k) o += ge[k] * Wf[k * DD + d];
    fc[b * DD + d] = o;
}

// ---- precompute: WkT[k][d] = W_node[d][k] (k<128);  W_og = W_out @ Wl^T ----
__global__ __launch_bounds__(128)
void precompute_w(const float* __restrict__ Wn, const float* __restrict__ Wout,
                  float* __restrict__ Wog, float* __restrict__ WkT) {
    int k = blockIdx.x, d = threadIdx.x;
    WkT[k * DD + d] = Wn[d * 384 + k];
    float s = 0.f;
    for (int e = 0; e < DD; ++e) s += Wout[k * DD + e] * Wn[d * 384 + 256 + e];
    Wog[k * DD + d] = s;
}

// ---------------------------- main decoder ----------------------------------
// 1024 threads: thread = (n = tid>>1, hf = tid&1). E half-row in 16 NAMED
// float4 regs (64 VGPR) -> fits default 128-VGPR budget, no array alloca.
// LDS 162,528 B: buf 131072 (chunk staging; aliased as wpart), P 16416,
// qt 4096 (aliased part2), eb 4096, part 4096 (aliased logits), small rest.
struct SMv {
    float buf[2][NN][32];
    float P[HH][513];
    float qt[HH][DD];
    float eb[HH][DD];
    float part[HH][DD];
    float hc[DD];
    float qarr[DD];
    float fcs[DD];
    float curE[DD];
    float lw[16][HH];
    float redf[16];
    float redv[8];
    int   redi[8];
    float Mh[HH];
    float stat[2];
    int   cur;
    float rbv;
};

__global__ __launch_bounds__(1024)
void decoder(const float* __restrict__ E, const float* __restrict__ Ws,
             const float* __restrict__ Wn, const float* __restrict__ fc,
             const float* __restrict__ Wog, const float* __restrict__ WkT,
             float* __restrict__ out_logp, float* __restrict__ out_seq, int T) {
    __shared__ SMv sm;
    const int b = blockIdx.x, tid = threadIdx.x;
    const int lane = tid & 63, wv = tid >> 6;      // 16 waves
    const int n = tid >> 1, hf = tid & 1;          // node row, half
    const int h8 = tid >> 7, d128 = tid & 127;     // (head|group, dim) roles
    const float* Eb = E + (size_t)b * NN * DD;

    // ---- load this thread's half-row into 16 named float4 registers ----
    float4 e0, e1, e2, e3, e4, e5, e6, e7, e8, e9, e10, e11, e12, e13, e14, e15;
    {
        const float4* src4 = (const float4*)(Eb + n * DD + hf * 64);
#define LD(q) e##q = src4[q];
        FOR16(LD)
#undef LD
    }
    bool vis = false;
    if (tid < DD) sm.fcs[tid] = fc[b * DD + tid];
    // Rb = max_n ||E[n]||
    {
        float s = 0.f;
#define NRM(q) s += dot4(e##q, e##q);
        FOR16(NRM)
#undef NRM
        s += __shfl_xor(s, 1);                     // full row norm^2 (both lanes)
        for (int o = 2; o < 64; o <<= 1) s = fmaxf(s, __shfl_xor(s, o));
        if (lane == 0) sm.redf[wv] = s;
    }
    if (tid == 0) sm.cur = 0;
    if (n == 0) {                                  // row 0 -> curE
        float* cd = &sm.curE[hf * 64];
#define WC(q) *(float4*)(cd + 4 * (q)) = e##q;
        FOR16(WC)
#undef WC
    }
    __syncthreads();
    if (tid == 0) {
        float m = sm.redf[0];
        for (int i = 1; i < 16; ++i) m = fmaxf(m, sm.redf[i]);
        sm.rbv = sqrtf(m);
    }
    __syncthreads();

    float* const lgp = &sm.part[0][0];             // logits alias
    float* const p2  = &sm.qt[0][0];               // part2 alias
    float* const wp  = &sm.buf[0][0][0];           // wave-partial alias

    for (int t = 0; t < T; ++t) {
        // ---- phase 0: q = fc + curE@Ws + frac*Ws_last (8 k-groups of 16) ----
        {
            float s = 0.f;
            const float* Wsg = Ws + d128;
            int k0 = h8 * 16;
            #pragma unroll
            for (int j = 0; j < 16; ++j) s += sm.curE[k0 + j] * Wsg[(k0 + j) * DD];
            if (h8 == 7) s += ((float)t / (float)T) * Wsg[DD * DD];
            sm.part[h8][d128] = s;
        }
        __syncthreads();
        if (tid < DD) {
            float s = sm.fcs[tid];
            #pragma unroll
            for (int g = 0; g < 8; ++g) s += sm.part[g][tid];
            sm.qarr[tid] = s;
        }
        __syncthreads();
        // ---- phase 0b: qt[h][d] (0.25 folded) + Cauchy-Schwarz bound ----
        {
            float a = 0.f;
            const float* WA = WkT + (h8 * 16) * DD + d128;
            #pragma unroll
            for (int j = 0; j < 16; ++j) a += sm.qarr[h8 * 16 + j] * WA[j * DD];
            a *= 0.25f;
            sm.qt[h8][d128] = a;
            float sa = a * a;
            for (int o = 1; o < 64; o <<= 1) sa += __shfl_xor(sa, o);
            if (lane == 0) sm.redf[wv] = sa;
        }
        __syncthreads();
        if (tid < 8)
            sm.Mh[tid] = sqrtf(sm.redf[2 * tid] + sm.redf[2 * tid + 1]) * sm.rbv;
        __syncthreads();

        // ---- compat + exp from registers (pair-combine via shfl_xor 1) ----
        for (int h = 0; h < 8; ++h) {
            const float* qh = &sm.qt[h][hf * 64];
            float s = 0.f;
#define CQT(q) { float4 qv = *(const float4*)(qh + 4 * (q)); s += dot4(qv, e##q); }
            FOR16(CQT)
#undef CQT
            s += __shfl_xor(s, 1);
            float p = vis ? 0.f : expf(s - sm.Mh[h]);
            if (hf == 0) sm.P[h][n] = p;
        }
        __syncthreads();

        // ---- e-bar: two staged chunk passes; wave wv owns n in [wv*32, +32) ----
        const int eh = lane >> 3, edq = lane & 7;
        const int nb = wv * 32;
        float4 aA0 = {0, 0, 0, 0}, aA1 = {0, 0, 0, 0};
        float4 aB0 = {0, 0, 0, 0}, aB1 = {0, 0, 0, 0};
        float lacc = 0.f;
        // pass A: stage e0..e7 (d = hf*64 .. +32)
#define ST(j, ev) *(float4*)&sm.buf[hf][n][(((j) ^ (n & 7)) * 4)] = ev;
        ST(0, e0) ST(1, e1) ST(2, e2) ST(3, e3)
        ST(4, e4) ST(5, e5) ST(6, e6) ST(7, e7)
        __syncthreads();
        #pragma unroll 8
        for (int i = 0; i < 32; ++i) {
            int nn = nb + i;
            float pv = sm.P[eh][nn];
            int c = ((edq ^ (nn & 7)) * 4);
            float4 v0 = *(const float4*)&sm.buf[0][nn][c];
            float4 v1 = *(const float4*)&sm.buf[1][nn][c];
            aA0.x += pv * v0.x; aA0.y += pv * v0.y; aA0.z += pv * v0.z; aA0.w += pv * v0.w;
            aA1.x += pv * v1.x; aA1.y += pv * v1.y; aA1.z += pv * v1.z; aA1.w += pv * v1.w;
            lacc += pv;
        }
        if (edq == 0) sm.lw[wv][eh] = lacc;
        __syncthreads();
        // pass B: stage e8..e15 (d = hf*64+32 .. +64)
        ST(0, e8) ST(1, e9) ST(2, e10) ST(3, e11)
        ST(4, e12) ST(5, e13) ST(6, e14) ST(7, e15)
#undef ST
        __syncthreads();
        #pragma unroll 8
        for (int i = 0; i < 32; ++i) {
            int nn = nb + i;
            float pv = sm.P[eh][nn];
            int c = ((edq ^ (nn & 7)) * 4);
            float4 v0 = *(const float4*)&sm.buf[0][nn][c];
            float4 v1 = *(const float4*)&sm.buf[1][nn][c];
            aB0.x += pv * v0.x; aB0.y += pv * v0.y; aB0.z += pv * v0.z; aB0.w += pv * v0.w;
            aB1.x += pv * v1.x; aB1.y += pv * v1.y; aB1.z += pv * v1.z; aB1.w += pv * v1.w;
        }
        __syncthreads();
        {   // wave partials -> wp (buf alias), slots: aA0,aA1,aB0,aB1
            float* wpe = wp + (size_t)(wv * 64 + eh * 8 + edq) * 20;
            *(float4*)&wpe[0]  = aA0;
            *(float4*)&wpe[4]  = aA1;
            *(float4*)&wpe[8]  = aB0;
            *(float4*)&wpe[12] = aB1;
        }
        __syncthreads();
        {   // combine 16 wave partials -> eb[h][d] normalized; thread = (h8,d128)
            int s5 = d128 >> 5;
            int sidx = ((s5 & 1) << 1) | (s5 >> 1);   // d-range -> slot {0:0,1:2,2:1,3:3}
            int dq = (d128 >> 2) & 7, comp = d128 & 3;
            float lsum = 0.f;
            #pragma unroll
            for (int w = 0; w < 16; ++w) lsum += sm.lw[w][h8];
            float a = 0.f;
            #pragma unroll
            for (int w = 0; w < 16; ++w)
                a += wp[(size_t)(w * 64 + h8 * 8 + dq) * 20 + sidx * 4 + comp];
            sm.eb[h8][d128] = a * (1.0f / lsum);
        }
        __syncthreads();

        // ---- phase 2: hc = eb @ Wv ; g~ = hc @ W_og ----
        {
            float s = 0.f;
            const int e = d128;
            const float* Wvp = Wn + 128 + e;
            #pragma unroll
            for (int j = 0; j < 16; ++j) {
                int d = h8 * 16 + j;
                s += sm.eb[e >> 4][d] * Wvp[d * 384];
            }
            sm.part[h8][e] = s;
        }
        __syncthreads();
        if (tid < DD) {
            float s = 0.f;
            #pragma unroll
            for (int g = 0; g < 8; ++g) s += sm.part[g][tid];
            sm.hc[tid] = s;
        }
        __syncthreads();
        {
            float s = 0.f;
            #pragma unroll
            for (int j = 0; j < 16; ++j) {
                int k = h8 * 16 + j;
                s += sm.hc[k] * Wog[k * DD + d128];
            }
            p2[h8 * DD + d128] = s;
        }
        __syncthreads();
        if (tid < DD) {
            float s = 0.f;
            #pragma unroll
            for (int g = 0; g < 8; ++g) s += p2[g * DD + tid];
            sm.qarr[tid] = s * INV_SQRT_D;        // qarr reused as g~
        }
        __syncthreads();

        // ---- logits from registers ----
        {
            const float* gv = &sm.qarr[hf * 64];
            float s = 0.f;
#define GQT(q) { float4 qv = *(const float4*)(gv + 4 * (q)); s += dot4(qv, e##q); }
            FOR16(GQT)
#undef GQT
            s += __shfl_xor(s, 1);
            if (hf == 0) lgp[n] = vis ? NEGC : 10.0f * tanhf(s);
        }
        __syncthreads();

        // ---- phase 4: log_softmax + write + argmax (first-index ties) + update ----
        {
            float x = 0.f, lp = 0.f;
            if (tid < NN) {
                x = lgp[tid];
                float m = x;
                for (int o = 1; o < 64; o <<= 1) m = fmaxf(m, __shfl_xor(m, o));
                if (lane == 0) sm.redf[wv] = m;
            }
            __syncthreads();
            if (tid == 0) {
                float mm = sm.redf[0];
                for (int i = 1; i < 8; ++i) mm = fmaxf(mm, sm.redf[i]);
                sm.stat[0] = mm;
            }
            __syncthreads();
            if (tid < NN) {
                float sh = x - sm.stat[0];        // masked: -1e9 - m -> -1e9
                float ex = expf(sh);              // masked: exactly 0
                float ssum = ex;
                for (int o = 1; o < 64; o <<= 1) ssum += __shfl_xor(ssum, o);
                if (lane == 0) sm.redf[wv] = ssum;
                lp = sh;
            }
            __syncthreads();
            if (tid == 0) {
                float s8 = 0.f;
                for (int i = 0; i < 8; ++i) s8 += sm.redf[i];
                sm.stat[1] = logf(s8);
            }
            __syncthreads();
            if (tid < NN) {
                lp = lp - sm.stat[1];
                out_logp[((size_t)b * T + t) * NN + tid] = lp;
                float bv = lp; int bi = tid;
                for (int o = 1; o < 64; o <<= 1) {
                    float ov = __shfl_xor(bv, o);
                    int   oi = __shfl_xor(bi, o);
                    if (ov > bv || (ov == bv && oi < bi)) { bv = ov; bi = oi; }
                }
                if (lane == 0) { sm.redv[wv] = bv; sm.redi[wv] = bi; }
            }
            __syncthreads();
            if (tid == 0) {
                float best = sm.redv[0]; int besti = sm.redi[0];
                for (int i = 1; i < 8; ++i) {
                    float ov = sm.redv[i]; int oi = sm.redi[i];
                    if (ov > best || (ov == best && oi < besti)) { best = ov; besti = oi; }
                }
                sm.cur = besti;
                out_seq[(size_t)b * T + t] = (float)besti;
            }
            __syncthreads();
            if (n == sm.cur) {                    // selected row -> curE, mark visited
                vis = true;
                float* cd = &sm.curE[hf * 64];
#define WC(q) *(float4*)(cd + 4 * (q)) = e##q;
                FOR16(WC)
#undef WC
            }
            __syncthreads();
        }
    }
}

// ------------------------------- launcher -----------------------------------
extern "C" void kernel_launch(void* const* d_in, const int* in_sizes, int n_in,
                              void* d_out, int out_size, void* d_ws, size_t ws_size,
                              hipStream_t stream) {
    const float* E    = (const float*)d_in[0];   // [B,N,D]
    const float* Wn   = (const float*)d_in[1];   // [D,3D]
    const float* Wf   = (const float*)d_in[2];   // [D,D]
    const float* Ws   = (const float*)d_in[3];   // [D+1,D]
    const float* Wout = (const float*)d_in[4];   // [D,D]
    float* out = (float*)d_out;

    const int T = out_size / (BB * (NN + 1));    // = num_steps (64)

    float* fc  = (float*)d_ws;                   // [B,D]
    float* Wog = fc + BB * DD;                   // [128,128]
    float* WkT = Wog + DD * DD;                  // [128,128]

    precompute_fc<<<BB, 128, 0, stream>>>(E, Wf, fc);
    precompute_w<<<DD, 128, 0, stream>>>(Wn, Wout, Wog, WkT);
    decoder<<<BB, 1024, 0, stream>>>(E, Ws, Wn, fc, Wog, WkT,
                                     out, out + (size_t)BB * T * NN, T);
}